// Round 15
// baseline (210.010 us; speedup 1.0000x reference)
//
#include <hip/hip_runtime.h>

typedef unsigned short u16;
typedef __bf16 bf16x8 __attribute__((ext_vector_type(8)));
typedef float f32x4 __attribute__((ext_vector_type(4)));

#define B_SZ 256
#define T_SZ 256
#define C_EMB 384
#define NHEAD 6
#define DHEAD 64
#define N3 1152
#define BHTD 25165824   // B*H*T*D elements per tensor
#define SCALE 0.05103103630798287f  // 384^-0.5
#define MASKV -3.0e4f   // causal-mask value: exp(MASKV) underflows to exact 0

// f32 -> bf16 RNE via compiler cast (single v_cvt instruction on gfx950)
__device__ __forceinline__ u16 f2bf(float f) {
  __bf16 b = (__bf16)f;
  return __builtin_bit_cast(u16, b);
}

__device__ __forceinline__ void gload_lds16(const void* g, void* l) {
  __builtin_amdgcn_global_load_lds((const __attribute__((address_space(1))) void*)g,
                                   (__attribute__((address_space(3))) void*)l, 16, 0, 0);
}

// ---------------- fused prep: x->bf16 AND weights->bf16 transposed ----------
__global__ __launch_bounds__(256) void prep_all(
    const float* __restrict__ x, const float* __restrict__ wk,
    const float* __restrict__ wq, const float* __restrict__ wv,
    const float* __restrict__ wproj,
    u16* __restrict__ xb, u16* __restrict__ wqkvt, u16* __restrict__ wprojt) {
  int bidx = blockIdx.x;
  if (bidx < 12288) {
    int i = bidx * 256 + threadIdx.x;   // unit of 8 floats
    float4 f0 = ((const float4*)x)[i * 2];
    float4 f1 = ((const float4*)x)[i * 2 + 1];
    uint4 p;
    p.x = (unsigned)f2bf(f0.x) | ((unsigned)f2bf(f0.y) << 16);
    p.y = (unsigned)f2bf(f0.z) | ((unsigned)f2bf(f0.w) << 16);
    p.z = (unsigned)f2bf(f1.x) | ((unsigned)f2bf(f1.y) << 16);
    p.w = (unsigned)f2bf(f1.z) | ((unsigned)f2bf(f1.w) << 16);
    ((uint4*)xb)[i] = p;
  } else {
    int i = (bidx - 12288) * 256 + threadIdx.x;
    if (i < N3 * C_EMB) {
      int n = i / C_EMB, c = i - n * C_EMB;
      int tensor = n >= 768 ? 2 : (n >= 384 ? 1 : 0);
      int r = n - tensor * 384;
      int h = r >> 6, d = r & 63;
      const float* w = tensor == 0 ? wk : (tensor == 1 ? wq : wv);
      float val = w[(h * C_EMB + c) * DHEAD + d];
      if (tensor == 0) val *= SCALE;   // fold 1/sqrt(C) into K
      wqkvt[i] = f2bf(val);
    } else {
      int ii = i - N3 * C_EMB;
      if (ii < C_EMB * C_EMB) {
        int n = ii / C_EMB, c = ii - n * C_EMB;
        wprojt[ii] = f2bf(wproj[c * C_EMB + n]);  // transpose
      }
    }
  }
}

// ---------------- QKV GEMM: 128x128 tile, BK=64, single-buffered (m97) ------
// FROZEN (round-9 verified; 822 TF = structure ceiling, retiles regress).
// K,Q stored [b][h][t][d]; V stored [b][h][d][t] (transposed).
__global__ __launch_bounds__(256, 4) void qkv_gemm(const u16* __restrict__ xb,
                                                   const u16* __restrict__ wt,
                                                   u16* __restrict__ kqv) {
  __shared__ __align__(16) u16 lA[128 * 64];
  __shared__ __align__(16) u16 lB[128 * 64];
  const int tid = threadIdx.x;
  const int lane = tid & 63, w = tid >> 6;
  int bid = blockIdx.x;
  int nb = (bid & 7) * 576 + (bid >> 3);
  int mt = nb / 9, nt = nb - mt * 9;
  const int n0 = nt * 128, m0 = mt * 128;
  const int wr = w >> 1, wc = w & 1;
  f32x4 acc[4][4] = {};
  for (int kt = 0; kt < 6; ++kt) {
    const int k0 = kt * 64;
#pragma unroll
    for (int it = 0; it < 4; ++it) {
      int ub = it * 256 + w * 64;
      int u = ub + lane;
      int row = u >> 3, cu = u & 7;
      int koff = k0 + ((cu ^ (row & 7)) << 3);
      gload_lds16(xb + (size_t)(m0 + row) * C_EMB + koff, lA + ub * 8);
      gload_lds16(wt + (size_t)(n0 + row) * C_EMB + koff, lB + ub * 8);
    }
    asm volatile("s_waitcnt vmcnt(0)" ::: "memory");
    asm volatile("s_barrier" ::: "memory");
    bf16x8 af[4][2], bfr[4][2];
#pragma unroll
    for (int mi = 0; mi < 4; ++mi) {
      int row = wr * 64 + mi * 16 + (lane & 15);
#pragma unroll
      for (int kk = 0; kk < 2; ++kk) {
        int cu = kk * 4 + (lane >> 4);
        af[mi][kk] = *(const bf16x8*)((const char*)lA + row * 128 + ((cu ^ (row & 7)) << 4));
      }
    }
#pragma unroll
    for (int ni = 0; ni < 4; ++ni) {
      int row = wc * 64 + ni * 16 + (lane & 15);
#pragma unroll
      for (int kk = 0; kk < 2; ++kk) {
        int cu = kk * 4 + (lane >> 4);
        bfr[ni][kk] = *(const bf16x8*)((const char*)lB + row * 128 + ((cu ^ (row & 7)) << 4));
      }
    }
#pragma unroll
    for (int kk = 0; kk < 2; ++kk)
#pragma unroll
      for (int mi = 0; mi < 4; ++mi)
#pragma unroll
        for (int ni = 0; ni < 4; ++ni)
          acc[mi][ni] = __builtin_amdgcn_mfma_f32_16x16x32_bf16(
              af[mi][kk], bfr[ni][kk], acc[mi][ni], 0, 0, 0);
    asm volatile("s_barrier" ::: "memory");   // all reads done before next stage
  }

  const int tensor = nt / 3;  // 128-tile lies in one tensor (384 = 3*128)
  if (tensor == 2) {
    // V^T store: vt[((b*6+h)*64 + d)*256 + t], 4 t-contiguous values packed
    u16* vt = kqv + 2 * (size_t)BHTD;
#pragma unroll
    for (int ni = 0; ni < 4; ++ni) {
      int r2 = n0 + wc * 64 + ni * 16 + (lane & 15) - 768;
      int h = r2 >> 6, d = r2 & 63;
#pragma unroll
      for (int mi = 0; mi < 4; ++mi) {
        int gm0 = m0 + wr * 64 + mi * 16 + ((lane >> 4) << 2);
        int b = gm0 >> 8, tt2 = gm0 & 255;
        ushort4 pk;
        pk.x = f2bf(acc[mi][ni][0]);
        pk.y = f2bf(acc[mi][ni][1]);
        pk.z = f2bf(acc[mi][ni][2]);
        pk.w = f2bf(acc[mi][ni][3]);
        *(ushort4*)(vt + ((size_t)(b * NHEAD + h) * 64 + d) * 256 + tt2) = pk;
      }
    }
  } else {
#pragma unroll
    for (int ni = 0; ni < 4; ++ni) {
      int gn = n0 + wc * 64 + ni * 16 + (lane & 15);
      int r2 = gn - tensor * 384;
      int h = r2 >> 6, d = r2 & 63;
#pragma unroll
      for (int mi = 0; mi < 4; ++mi) {
        int gm0 = m0 + wr * 64 + mi * 16 + ((lane >> 4) << 2);
#pragma unroll
        for (int r = 0; r < 4; ++r) {
          int m = gm0 + r;
          int b = m >> 8, t = m & 255;
          kqv[(size_t)tensor * BHTD + ((((b * NHEAD + h) << 8) + t) << 6) + d] =
              f2bf(acc[mi][ni][r]);
        }
      }
    }
  }
}

// ---------------- causal flash attention, S[t,s] = Ksc[t]·Q[s] ----
// ONE block per (b,h). V is NOT LDS-staged (32KB: L1-resident after first
// touch, L2-hot from qkv) -> LDS 48KB -> 3 blocks/CU. PV reads V^T fragments
// directly from global. Complementary row-groups: 5 causal tiles per wave.
__global__ __launch_bounds__(512, 2) void attn_kernel(const u16* __restrict__ kqv,
                                                      u16* __restrict__ attnb) {
  __shared__ __align__(16) u16 lQ[256 * 64];    // 32KB, [s][d] swz
  __shared__ __align__(16) char lP[8 * 16 * 128]; // 16KB, per-wave XOR-swz
  const int tid = threadIdx.x;
  const int lane = tid & 63, w = tid >> 6;
  int bid = blockIdx.x;                       // 1536 = 8 * 192
  const int bh = (bid & 7) * 192 + (bid >> 3);
  const u16* Kb = kqv + (size_t)bh * (T_SZ * DHEAD);
  const u16* Qb = kqv + (size_t)BHTD + (size_t)bh * (T_SZ * DHEAD);
  const u16* Vb = kqv + 2 * (size_t)BHTD + (size_t)bh * (DHEAD * T_SZ);  // [d][t]

  const int t0w0 = w * 16;                    // row-group 0 (early rows)
  const int t0w1 = 240 - w * 16;              // row-group 1 (complement: balance)
  const int tg00 = t0w0 + ((lane >> 4) << 2);
  const int tg01 = t0w1 + ((lane >> 4) << 2);

  // --- issue order (fenced): K->regs (oldest), Q rows 0-63, Q rest ---
  bf16x8 af0[2], af1[2];
  {
    const u16* kr0 = Kb + (size_t)(t0w0 + (lane & 15)) * DHEAD;
    const u16* kr1 = Kb + (size_t)(t0w1 + (lane & 15)) * DHEAD;
    af0[0] = *(const bf16x8*)(kr0 + ((lane >> 4) << 3));
    af0[1] = *(const bf16x8*)(kr0 + 32 + ((lane >> 4) << 3));
    af1[0] = *(const bf16x8*)(kr1 + ((lane >> 4) << 3));
    af1[1] = *(const bf16x8*)(kr1 + 32 + ((lane >> 4) << 3));
  }
  asm volatile("" ::: "memory");
  {                                           // Q tile 0: rows 0-63 (1 load)
    int u = tid;
    int row = u >> 3, cu = u & 7;
    gload_lds16(Qb + (size_t)row * DHEAD + ((cu ^ (row & 7)) << 3), lQ + u * 8);
  }
  asm volatile("" ::: "memory");
#pragma unroll
  for (int it = 1; it < 4; ++it) {            // Q rows 64-255 (3 loads)
    int u = it * 512 + tid;
    int row = u >> 3, cu = u & 7;
    gload_lds16(Qb + (size_t)row * DHEAD + ((cu ^ (row & 7)) << 3), lQ + u * 8);
  }
  // K(4)+Q0(1) retired; Q-rest(3) still in flight
  asm volatile("s_waitcnt vmcnt(3)" ::: "memory");
  asm volatile("s_barrier" ::: "memory");            // lQ rows 0-63 ready

  char* lPw = lP + w * (16 * 128);
  f32x4 oacc0[4] = {}, oacc1[4] = {};
  float lrowp0[4] = {0.f, 0.f, 0.f, 0.f};
  float lrowp1[4] = {0.f, 0.f, 0.f, 0.f};
  const int last0 = t0w0 >> 6;                // 0..1
  const int last1 = t0w1 >> 6;                // 3..2  (complement)

#define QK_TILE(s0_, af_, t0w_, tg0_, lrp_) { \
    f32x4 sacc[4] = {}; \
    __builtin_amdgcn_s_setprio(1); \
    _Pragma("unroll") for (int ni = 0; ni < 4; ++ni) { \
      int row = (s0_) + ni * 16 + (lane & 15); \
      _Pragma("unroll") for (int kk = 0; kk < 2; ++kk) { \
        int cu = kk * 4 + (lane >> 4); \
        bf16x8 bq = *(const bf16x8*)((const char*)lQ + row * 128 + ((cu ^ (row & 7)) << 4)); \
        sacc[ni] = __builtin_amdgcn_mfma_f32_16x16x32_bf16(af_[kk], bq, sacc[ni], 0, 0, 0); \
      } \
    } \
    __builtin_amdgcn_s_setprio(0); \
    if ((s0_) + 63 > (t0w_)) { \
      _Pragma("unroll") for (int ni = 0; ni < 4; ++ni) { \
        int sg = (s0_) + ni * 16 + (lane & 15); \
        _Pragma("unroll") for (int r = 0; r < 4; ++r) \
          if (sg > (tg0_) + r) sacc[ni][r] = MASKV; \
      } \
    } \
    _Pragma("unroll") for (int ni = 0; ni < 4; ++ni) { \
      int scol = ni * 16 + (lane & 15); \
      _Pragma("unroll") for (int r = 0; r < 4; ++r) { \
        float p = __expf(sacc[ni][r]); \
        lrp_[r] += p; \
        int trow = ((lane >> 4) << 2) + r; \
        *(u16*)(lPw + trow * 128 + ((scol * 2) ^ ((trow & 7) << 4))) = f2bf(p); \
      } \
    } }

#define PV_TILE(s0_, oacc_) { \
    bf16x8 pa[2]; \
    int trow = lane & 15; \
    _Pragma("unroll") for (int kk = 0; kk < 2; ++kk) { \
      int cu = kk * 4 + (lane >> 4); \
      pa[kk] = *(const bf16x8*)(lPw + trow * 128 + (((cu) << 4) ^ ((trow & 7) << 4))); \
    } \
    __builtin_amdgcn_s_setprio(1); \
    _Pragma("unroll") for (int nd = 0; nd < 4; ++nd) { \
      int drow = nd * 16 + (lane & 15); \
      _Pragma("unroll") for (int kk = 0; kk < 2; ++kk) { \
        int cu = kk * 4 + (lane >> 4); \
        bf16x8 vb = *(const bf16x8*)(Vb + (size_t)drow * 256 + (s0_) + cu * 8); \
        oacc_[nd] = __builtin_amdgcn_mfma_f32_16x16x32_bf16(pa[kk], vb, oacc_[nd], 0, 0, 0); \
      } \
    } \
    __builtin_amdgcn_s_setprio(0); }

  // row-group 0, tile 0: QK+softmax overlaps Q-rest in-flight loads
  QK_TILE(0, af0, t0w0, tg00, lrowp0)
  asm volatile("s_waitcnt vmcnt(0)" ::: "memory");   // Q-rest landed
  asm volatile("s_barrier" ::: "memory");            // lQ fully ready
  PV_TILE(0, oacc0)
  for (int si = 1; si <= last0; ++si) {
    const int s0 = si << 6;
    QK_TILE(s0, af0, t0w0, tg00, lrowp0)
    PV_TILE(s0, oacc0)
  }
  // row-group 1: barrier-free
  for (int si = 0; si <= last1; ++si) {
    const int s0 = si << 6;
    QK_TILE(s0, af1, t0w1, tg01, lrowp1)
    PV_TILE(s0, oacc1)
  }
#undef QK_TILE
#undef PV_TILE

  // final cross-lane row-sum reduce (once per group)
#pragma unroll
  for (int r = 0; r < 4; ++r) {
#pragma unroll
    for (int off = 1; off < 16; off <<= 1) {
      lrowp0[r] += __shfl_xor(lrowp0[r], off);
      lrowp1[r] += __shfl_xor(lrowp1[r], off);
    }
  }
  const int b = bh / NHEAD, h = bh - (bh / NHEAD) * NHEAD;
#pragma unroll
  for (int r = 0; r < 4; ++r) {
    int t0_ = tg00 + r, t1_ = tg01 + r;
    float inv0 = 1.0f / lrowp0[r];
    float inv1 = 1.0f / lrowp1[r];
#pragma unroll
    for (int nd = 0; nd < 4; ++nd) {
      int col = h * 64 + nd * 16 + (lane & 15);
      attnb[((size_t)(b * T_SZ + t0_)) * C_EMB + col] = f2bf(oacc0[nd][r] * inv0);
      attnb[((size_t)(b * T_SZ + t1_)) * C_EMB + col] = f2bf(oacc1[nd][r] * inv1);
    }
  }
}

// ---------------- out projection: 128x128 tile, single-buffered -------------
__global__ __launch_bounds__(256, 4) void out_gemm(const u16* __restrict__ a,
                                                   const u16* __restrict__ wt,
                                                   const float* __restrict__ bias,
                                                   float* __restrict__ out) {
  __shared__ __align__(16) u16 lA[128 * 64];
  __shared__ __align__(16) u16 lB[128 * 64];
  const int tid = threadIdx.x;
  const int lane = tid & 63, w = tid >> 6;
  int bid = blockIdx.x;
  int nb = (bid & 7) * 192 + (bid >> 3);
  int mt = nb / 3, nt = nb - mt * 3;
  const int n0 = nt * 128, m0 = mt * 128;
  const int wr = w >> 1, wc = w & 1;
  f32x4 acc[4][4] = {};
  for (int kt = 0; kt < 6; ++kt) {
    const int k0 = kt * 64;
#pragma unroll
    for (int it = 0; it < 4; ++it) {
      int ub = it * 256 + w * 64;
      int u = ub + lane;
      int row = u >> 3, cu = u & 7;
      int koff = k0 + ((cu ^ (row & 7)) << 3);
      gload_lds16(a + (size_t)(m0 + row) * C_EMB + koff, lA + ub * 8);
      gload_lds16(wt + (size_t)(n0 + row) * C_EMB + koff, lB + ub * 8);
    }
    asm volatile("s_waitcnt vmcnt(0)" ::: "memory");
    asm volatile("s_barrier" ::: "memory");
    bf16x8 af[4][2], bfr[4][2];
#pragma unroll
    for (int mi = 0; mi < 4; ++mi) {
      int row = wr * 64 + mi * 16 + (lane & 15);
#pragma unroll
      for (int kk = 0; kk < 2; ++kk) {
        int cu = kk * 4 + (lane >> 4);
        af[mi][kk] = *(const bf16x8*)((const char*)lA + row * 128 + ((cu ^ (row & 7)) << 4));
      }
    }
#pragma unroll
    for (int ni = 0; ni < 4; ++ni) {
      int row = wc * 64 + ni * 16 + (lane & 15);
#pragma unroll
      for (int kk = 0; kk < 2; ++kk) {
        int cu = kk * 4 + (lane >> 4);
        bfr[ni][kk] = *(const bf16x8*)((const char*)lB + row * 128 + ((cu ^ (row & 7)) << 4));
      }
    }
#pragma unroll
    for (int kk = 0; kk < 2; ++kk)
#pragma unroll
      for (int mi = 0; mi < 4; ++mi)
#pragma unroll
        for (int ni = 0; ni < 4; ++ni)
          acc[mi][ni] = __builtin_amdgcn_mfma_f32_16x16x32_bf16(
              af[mi][kk], bfr[ni][kk], acc[mi][ni], 0, 0, 0);
    asm volatile("s_barrier" ::: "memory");
  }
#pragma unroll
  for (int ni = 0; ni < 4; ++ni) {
    int gn = n0 + wc * 64 + ni * 16 + (lane & 15);
    float bv = bias[gn];
#pragma unroll
    for (int mi = 0; mi < 4; ++mi) {
      int gm0 = m0 + wr * 64 + mi * 16 + ((lane >> 4) << 2);
#pragma unroll
      for (int r = 0; r < 4; ++r)
        out[(size_t)(gm0 + r) * C_EMB + gn] = acc[mi][ni][r] + bv;
    }
  }
}

extern "C" void kernel_launch(void* const* d_in, const int* in_sizes, int n_in,
                              void* d_out, int out_size, void* d_ws, size_t ws_size,
                              hipStream_t stream) {
  const float* x = (const float*)d_in[0];
  const float* wk = (const float*)d_in[1];
  const float* wq = (const float*)d_in[2];
  const float* wv = (const float*)d_in[3];
  const float* wproj = (const float*)d_in[4];
  const float* bproj = (const float*)d_in[5];
  float* out = (float*)d_out;
  u16* ws = (u16*)d_ws;
  u16* kqv = ws;                               // 3 * BHTD bf16 (K,Q [bhtd]; V [bhdt])
  u16* attnb = ws + 3 * (size_t)BHTD;          // BHTD bf16 (attn out)
  u16* xb = attnb;                             // aliases attnb: xb dead before attn writes
  u16* wqkvt = attnb + (size_t)BHTD;           // 1152*384
  u16* wprojt = wqkvt + (size_t)N3 * C_EMB;    // 384*384
  prep_all<<<14592, 256, 0, stream>>>(x, wk, wq, wv, wproj, xb, wqkvt, wprojt);
  qkv_gemm<<<4608, 256, 0, stream>>>(xb, wqkvt, kqv);
  attn_kernel<<<1536, 512, 0, stream>>>(kqv, attnb);
  out_gemm<<<1536, 256, 0, stream>>>(attnb, wprojt, bproj, out);
}

// Round 16
// 189.608 us; speedup vs baseline: 1.1076x; 1.1076x over previous
//
#include <hip/hip_runtime.h>

typedef unsigned short u16;
typedef __bf16 bf16x8 __attribute__((ext_vector_type(8)));
typedef float f32x4 __attribute__((ext_vector_type(4)));

#define B_SZ 256
#define T_SZ 256
#define C_EMB 384
#define NHEAD 6
#define DHEAD 64
#define N3 1152
#define BHTD 25165824   // B*H*T*D elements per tensor
#define SCALE 0.05103103630798287f  // 384^-0.5
#define MASKV -3.0e4f   // causal-mask value: exp(MASKV) underflows to exact 0

// f32 -> bf16 RNE via compiler cast (single v_cvt instruction on gfx950)
__device__ __forceinline__ u16 f2bf(float f) {
  __bf16 b = (__bf16)f;
  return __builtin_bit_cast(u16, b);
}

__device__ __forceinline__ void gload_lds16(const void* g, void* l) {
  __builtin_amdgcn_global_load_lds((const __attribute__((address_space(1))) void*)g,
                                   (__attribute__((address_space(3))) void*)l, 16, 0, 0);
}

// ---------------- fused prep: x->bf16 AND weights->bf16 transposed ----------
__global__ __launch_bounds__(256) void prep_all(
    const float* __restrict__ x, const float* __restrict__ wk,
    const float* __restrict__ wq, const float* __restrict__ wv,
    const float* __restrict__ wproj,
    u16* __restrict__ xb, u16* __restrict__ wqkvt, u16* __restrict__ wprojt) {
  int bidx = blockIdx.x;
  if (bidx < 12288) {
    int i = bidx * 256 + threadIdx.x;   // unit of 8 floats
    float4 f0 = ((const float4*)x)[i * 2];
    float4 f1 = ((const float4*)x)[i * 2 + 1];
    uint4 p;
    p.x = (unsigned)f2bf(f0.x) | ((unsigned)f2bf(f0.y) << 16);
    p.y = (unsigned)f2bf(f0.z) | ((unsigned)f2bf(f0.w) << 16);
    p.z = (unsigned)f2bf(f1.x) | ((unsigned)f2bf(f1.y) << 16);
    p.w = (unsigned)f2bf(f1.z) | ((unsigned)f2bf(f1.w) << 16);
    ((uint4*)xb)[i] = p;
  } else {
    int i = (bidx - 12288) * 256 + threadIdx.x;
    if (i < N3 * C_EMB) {
      int n = i / C_EMB, c = i - n * C_EMB;
      int tensor = n >= 768 ? 2 : (n >= 384 ? 1 : 0);
      int r = n - tensor * 384;
      int h = r >> 6, d = r & 63;
      const float* w = tensor == 0 ? wk : (tensor == 1 ? wq : wv);
      float val = w[(h * C_EMB + c) * DHEAD + d];
      if (tensor == 0) val *= SCALE;   // fold 1/sqrt(C) into K
      wqkvt[i] = f2bf(val);
    } else {
      int ii = i - N3 * C_EMB;
      if (ii < C_EMB * C_EMB) {
        int n = ii / C_EMB, c = ii - n * C_EMB;
        wprojt[ii] = f2bf(wproj[c * C_EMB + n]);  // transpose
      }
    }
  }
}

// ---------------- QKV GEMM: 128x128 tile, BK=64, single-buffered (m97) ------
// FROZEN (round-9 verified; 822 TF = structure ceiling, retiles regress).
// K,Q stored [b][h][t][d]; V stored [b][h][d][t] (transposed).
__global__ __launch_bounds__(256, 4) void qkv_gemm(const u16* __restrict__ xb,
                                                   const u16* __restrict__ wt,
                                                   u16* __restrict__ kqv) {
  __shared__ __align__(16) u16 lA[128 * 64];
  __shared__ __align__(16) u16 lB[128 * 64];
  const int tid = threadIdx.x;
  const int lane = tid & 63, w = tid >> 6;
  int bid = blockIdx.x;
  int nb = (bid & 7) * 576 + (bid >> 3);
  int mt = nb / 9, nt = nb - mt * 9;
  const int n0 = nt * 128, m0 = mt * 128;
  const int wr = w >> 1, wc = w & 1;
  f32x4 acc[4][4] = {};
  for (int kt = 0; kt < 6; ++kt) {
    const int k0 = kt * 64;
#pragma unroll
    for (int it = 0; it < 4; ++it) {
      int ub = it * 256 + w * 64;
      int u = ub + lane;
      int row = u >> 3, cu = u & 7;
      int koff = k0 + ((cu ^ (row & 7)) << 3);
      gload_lds16(xb + (size_t)(m0 + row) * C_EMB + koff, lA + ub * 8);
      gload_lds16(wt + (size_t)(n0 + row) * C_EMB + koff, lB + ub * 8);
    }
    asm volatile("s_waitcnt vmcnt(0)" ::: "memory");
    asm volatile("s_barrier" ::: "memory");
    bf16x8 af[4][2], bfr[4][2];
#pragma unroll
    for (int mi = 0; mi < 4; ++mi) {
      int row = wr * 64 + mi * 16 + (lane & 15);
#pragma unroll
      for (int kk = 0; kk < 2; ++kk) {
        int cu = kk * 4 + (lane >> 4);
        af[mi][kk] = *(const bf16x8*)((const char*)lA + row * 128 + ((cu ^ (row & 7)) << 4));
      }
    }
#pragma unroll
    for (int ni = 0; ni < 4; ++ni) {
      int row = wc * 64 + ni * 16 + (lane & 15);
#pragma unroll
      for (int kk = 0; kk < 2; ++kk) {
        int cu = kk * 4 + (lane >> 4);
        bfr[ni][kk] = *(const bf16x8*)((const char*)lB + row * 128 + ((cu ^ (row & 7)) << 4));
      }
    }
#pragma unroll
    for (int kk = 0; kk < 2; ++kk)
#pragma unroll
      for (int mi = 0; mi < 4; ++mi)
#pragma unroll
        for (int ni = 0; ni < 4; ++ni)
          acc[mi][ni] = __builtin_amdgcn_mfma_f32_16x16x32_bf16(
              af[mi][kk], bfr[ni][kk], acc[mi][ni], 0, 0, 0);
    asm volatile("s_barrier" ::: "memory");   // all reads done before next stage
  }

  const int tensor = nt / 3;  // 128-tile lies in one tensor (384 = 3*128)
  if (tensor == 2) {
    // V^T store: vt[((b*6+h)*64 + d)*256 + t], 4 t-contiguous values packed
    u16* vt = kqv + 2 * (size_t)BHTD;
#pragma unroll
    for (int ni = 0; ni < 4; ++ni) {
      int r2 = n0 + wc * 64 + ni * 16 + (lane & 15) - 768;
      int h = r2 >> 6, d = r2 & 63;
#pragma unroll
      for (int mi = 0; mi < 4; ++mi) {
        int gm0 = m0 + wr * 64 + mi * 16 + ((lane >> 4) << 2);
        int b = gm0 >> 8, tt2 = gm0 & 255;
        ushort4 pk;
        pk.x = f2bf(acc[mi][ni][0]);
        pk.y = f2bf(acc[mi][ni][1]);
        pk.z = f2bf(acc[mi][ni][2]);
        pk.w = f2bf(acc[mi][ni][3]);
        *(ushort4*)(vt + ((size_t)(b * NHEAD + h) * 64 + d) * 256 + tt2) = pk;
      }
    }
  } else {
#pragma unroll
    for (int ni = 0; ni < 4; ++ni) {
      int gn = n0 + wc * 64 + ni * 16 + (lane & 15);
      int r2 = gn - tensor * 384;
      int h = r2 >> 6, d = r2 & 63;
#pragma unroll
      for (int mi = 0; mi < 4; ++mi) {
        int gm0 = m0 + wr * 64 + mi * 16 + ((lane >> 4) << 2);
#pragma unroll
        for (int r = 0; r < 4; ++r) {
          int m = gm0 + r;
          int b = m >> 8, t = m & 255;
          kqv[(size_t)tensor * BHTD + ((((b * NHEAD + h) << 8) + t) << 6) + d] =
              f2bf(acc[mi][ni][r]);
        }
      }
    }
  }
}

// ---------------- causal flash attention, S[t,s] = Ksc[t]·Q[s] ----
// ONE block per (b,h); Q + V^T LDS-staged (r14 winner). NEW: T15 2-stage
// software pipeline over each wave's 5-tile schedule — QK(item i+1) issued
// BEFORE SMPV(item i) with double sacc buffers, so the exp/cvt VALU chain of
// tile i hides under tile i+1's QK MFMAs. Schedules are wave-uniform
// (w<4: groups {1,4}; w>=4: {2,3}) and fully static (no dynamic indexing).
__global__ __launch_bounds__(512, 2) void attn_kernel(const u16* __restrict__ kqv,
                                                      u16* __restrict__ attnb) {
  __shared__ __align__(16) u16 lQ[256 * 64];    // 32KB, [s][d] swz
  __shared__ __align__(16) u16 lVt[64 * 256];   // 32KB, [d][s] stride 512B swz
  __shared__ __align__(16) char lP[8 * 16 * 128]; // 16KB, per-wave XOR-swz
  const int tid = threadIdx.x;
  const int lane = tid & 63, w = tid >> 6;
  int bid = blockIdx.x;                       // 1536 = 8 * 192
  const int bh = (bid & 7) * 192 + (bid >> 3);
  const u16* Kb = kqv + (size_t)bh * (T_SZ * DHEAD);
  const u16* Qb = kqv + (size_t)BHTD + (size_t)bh * (T_SZ * DHEAD);
  const u16* Vb = kqv + 2 * (size_t)BHTD + (size_t)bh * (DHEAD * T_SZ);  // [d][t]

  const int t0w0 = w * 16;                    // row-group 0 (early rows)
  const int t0w1 = 240 - w * 16;              // row-group 1 (complement: balance)
  const int tg00 = t0w0 + ((lane >> 4) << 2);
  const int tg01 = t0w1 + ((lane >> 4) << 2);

  // --- issue order (fenced): K->regs (oldest), Q rows 0-63, Q rest, V ---
  bf16x8 af0[2], af1[2];
  {
    const u16* kr0 = Kb + (size_t)(t0w0 + (lane & 15)) * DHEAD;
    const u16* kr1 = Kb + (size_t)(t0w1 + (lane & 15)) * DHEAD;
    af0[0] = *(const bf16x8*)(kr0 + ((lane >> 4) << 3));
    af0[1] = *(const bf16x8*)(kr0 + 32 + ((lane >> 4) << 3));
    af1[0] = *(const bf16x8*)(kr1 + ((lane >> 4) << 3));
    af1[1] = *(const bf16x8*)(kr1 + 32 + ((lane >> 4) << 3));
  }
  asm volatile("" ::: "memory");
  {                                           // Q tile 0: rows 0-63 (1 load)
    int u = tid;
    int row = u >> 3, cu = u & 7;
    gload_lds16(Qb + (size_t)row * DHEAD + ((cu ^ (row & 7)) << 3), lQ + u * 8);
  }
  asm volatile("" ::: "memory");
#pragma unroll
  for (int it = 1; it < 4; ++it) {            // Q rows 64-255 (3 loads)
    int u = it * 512 + tid;
    int row = u >> 3, cu = u & 7;
    gload_lds16(Qb + (size_t)row * DHEAD + ((cu ^ (row & 7)) << 3), lQ + u * 8);
  }
  asm volatile("" ::: "memory");
#pragma unroll
  for (int it = 0; it < 4; ++it) {            // V^T: 64 rows x 256s, swz/128B win
    int u = it * 512 + tid;
    int row = u >> 5, cu = u & 31;
    gload_lds16(Vb + (size_t)row * T_SZ + ((cu >> 3) << 6) + (((cu & 7) ^ (row & 7)) << 3),
                lVt + u * 8);
  }
  // K(4)+Q0(1) retired; Q-rest(3)+V(4)=7 still in flight
  asm volatile("s_waitcnt vmcnt(7)" ::: "memory");
  asm volatile("s_barrier" ::: "memory");            // lQ rows 0-63 ready

  char* lPw = lP + w * (16 * 128);
  f32x4 oacc0[4] = {}, oacc1[4] = {};
  float lrowp0[4] = {0.f, 0.f, 0.f, 0.f};
  float lrowp1[4] = {0.f, 0.f, 0.f, 0.f};
  f32x4 saccA[4], saccB[4];

#define QKM(sacc_, af_, s0_) { \
    _Pragma("unroll") for (int ni = 0; ni < 4; ++ni) \
      sacc_[ni] = (f32x4){0.f, 0.f, 0.f, 0.f}; \
    __builtin_amdgcn_s_setprio(1); \
    _Pragma("unroll") for (int ni = 0; ni < 4; ++ni) { \
      int row = (s0_) + ni * 16 + (lane & 15); \
      _Pragma("unroll") for (int kk = 0; kk < 2; ++kk) { \
        int cu = kk * 4 + (lane >> 4); \
        bf16x8 bq = *(const bf16x8*)((const char*)lQ + row * 128 + ((cu ^ (row & 7)) << 4)); \
        sacc_[ni] = __builtin_amdgcn_mfma_f32_16x16x32_bf16(af_[kk], bq, sacc_[ni], 0, 0, 0); \
      } \
    } \
    __builtin_amdgcn_s_setprio(0); }

#define SMPV(sacc_, s0_, t0w_, tg0_, lrp_, oacc_) { \
    if ((s0_) + 63 > (t0w_)) { \
      _Pragma("unroll") for (int ni = 0; ni < 4; ++ni) { \
        int sg = (s0_) + ni * 16 + (lane & 15); \
        _Pragma("unroll") for (int r = 0; r < 4; ++r) \
          if (sg > (tg0_) + r) sacc_[ni][r] = MASKV; \
      } \
    } \
    _Pragma("unroll") for (int ni = 0; ni < 4; ++ni) { \
      int scol = ni * 16 + (lane & 15); \
      _Pragma("unroll") for (int r = 0; r < 4; ++r) { \
        float p = __expf(sacc_[ni][r]); \
        lrp_[r] += p; \
        int trow = ((lane >> 4) << 2) + r; \
        *(u16*)(lPw + trow * 128 + ((scol * 2) ^ ((trow & 7) << 4))) = f2bf(p); \
      } \
    } \
    { bf16x8 pa[2]; \
      int trow = lane & 15; \
      _Pragma("unroll") for (int kk = 0; kk < 2; ++kk) { \
        int cu = kk * 4 + (lane >> 4); \
        pa[kk] = *(const bf16x8*)(lPw + trow * 128 + (((cu) << 4) ^ ((trow & 7) << 4))); \
      } \
      __builtin_amdgcn_s_setprio(1); \
      _Pragma("unroll") for (int nd = 0; nd < 4; ++nd) { \
        int drow = nd * 16 + (lane & 15); \
        _Pragma("unroll") for (int kk = 0; kk < 2; ++kk) { \
          int cu = kk * 4 + (lane >> 4); \
          bf16x8 vb = *(const bf16x8*)((const char*)lVt + drow * 512 + (s0_) * 2 + \
                                       (((cu) ^ (drow & 7)) << 4)); \
          oacc_[nd] = __builtin_amdgcn_mfma_f32_16x16x32_bf16(pa[kk], vb, oacc_[nd], 0, 0, 0); \
        } \
      } \
      __builtin_amdgcn_s_setprio(0); } }

  // item0 = (g0, s0=0): QK overlaps Q-rest + V in-flight loads
  QKM(saccA, af0, 0)
  asm volatile("s_waitcnt vmcnt(0)" ::: "memory");   // Q-rest + V landed
  asm volatile("s_barrier" ::: "memory");            // lQ + lVt fully ready
  if (t0w0 < 64) {
    // w<4: g0 tiles {0}; g1 tiles {0,64,128,192}
    QKM(saccB, af1, 0)
    SMPV(saccA, 0,   t0w0, tg00, lrowp0, oacc0)
    QKM(saccA, af1, 64)
    SMPV(saccB, 0,   t0w1, tg01, lrowp1, oacc1)
    QKM(saccB, af1, 128)
    SMPV(saccA, 64,  t0w1, tg01, lrowp1, oacc1)
    QKM(saccA, af1, 192)
    SMPV(saccB, 128, t0w1, tg01, lrowp1, oacc1)
    SMPV(saccA, 192, t0w1, tg01, lrowp1, oacc1)
  } else {
    // w>=4: g0 tiles {0,64}; g1 tiles {0,64,128}
    QKM(saccB, af0, 64)
    SMPV(saccA, 0,   t0w0, tg00, lrowp0, oacc0)
    QKM(saccA, af1, 0)
    SMPV(saccB, 64,  t0w0, tg00, lrowp0, oacc0)
    QKM(saccB, af1, 64)
    SMPV(saccA, 0,   t0w1, tg01, lrowp1, oacc1)
    QKM(saccA, af1, 128)
    SMPV(saccB, 64,  t0w1, tg01, lrowp1, oacc1)
    SMPV(saccA, 128, t0w1, tg01, lrowp1, oacc1)
  }
#undef QKM
#undef SMPV

  // final cross-lane row-sum reduce (once per group)
#pragma unroll
  for (int r = 0; r < 4; ++r) {
#pragma unroll
    for (int off = 1; off < 16; off <<= 1) {
      lrowp0[r] += __shfl_xor(lrowp0[r], off);
      lrowp1[r] += __shfl_xor(lrowp1[r], off);
    }
  }
  const int b = bh / NHEAD, h = bh - (bh / NHEAD) * NHEAD;
#pragma unroll
  for (int r = 0; r < 4; ++r) {
    int t0_ = tg00 + r, t1_ = tg01 + r;
    float inv0 = 1.0f / lrowp0[r];
    float inv1 = 1.0f / lrowp1[r];
#pragma unroll
    for (int nd = 0; nd < 4; ++nd) {
      int col = h * 64 + nd * 16 + (lane & 15);
      attnb[((size_t)(b * T_SZ + t0_)) * C_EMB + col] = f2bf(oacc0[nd][r] * inv0);
      attnb[((size_t)(b * T_SZ + t1_)) * C_EMB + col] = f2bf(oacc1[nd][r] * inv1);
    }
  }
}

// ---------------- out projection: 128x128 tile, single-buffered -------------
__global__ __launch_bounds__(256, 4) void out_gemm(const u16* __restrict__ a,
                                                   const u16* __restrict__ wt,
                                                   const float* __restrict__ bias,
                                                   float* __restrict__ out) {
  __shared__ __align__(16) u16 lA[128 * 64];
  __shared__ __align__(16) u16 lB[128 * 64];
  const int tid = threadIdx.x;
  const int lane = tid & 63, w = tid >> 6;
  int bid = blockIdx.x;
  int nb = (bid & 7) * 192 + (bid >> 3);
  int mt = nb / 3, nt = nb - mt * 3;
  const int n0 = nt * 128, m0 = mt * 128;
  const int wr = w >> 1, wc = w & 1;
  f32x4 acc[4][4] = {};
  for (int kt = 0; kt < 6; ++kt) {
    const int k0 = kt * 64;
#pragma unroll
    for (int it = 0; it < 4; ++it) {
      int ub = it * 256 + w * 64;
      int u = ub + lane;
      int row = u >> 3, cu = u & 7;
      int koff = k0 + ((cu ^ (row & 7)) << 3);
      gload_lds16(a + (size_t)(m0 + row) * C_EMB + koff, lA + ub * 8);
      gload_lds16(wt + (size_t)(n0 + row) * C_EMB + koff, lB + ub * 8);
    }
    asm volatile("s_waitcnt vmcnt(0)" ::: "memory");
    asm volatile("s_barrier" ::: "memory");
    bf16x8 af[4][2], bfr[4][2];
#pragma unroll
    for (int mi = 0; mi < 4; ++mi) {
      int row = wr * 64 + mi * 16 + (lane & 15);
#pragma unroll
      for (int kk = 0; kk < 2; ++kk) {
        int cu = kk * 4 + (lane >> 4);
        af[mi][kk] = *(const bf16x8*)((const char*)lA + row * 128 + ((cu ^ (row & 7)) << 4));
      }
    }
#pragma unroll
    for (int ni = 0; ni < 4; ++ni) {
      int row = wc * 64 + ni * 16 + (lane & 15);
#pragma unroll
      for (int kk = 0; kk < 2; ++kk) {
        int cu = kk * 4 + (lane >> 4);
        bfr[ni][kk] = *(const bf16x8*)((const char*)lB + row * 128 + ((cu ^ (row & 7)) << 4));
      }
    }
#pragma unroll
    for (int kk = 0; kk < 2; ++kk)
#pragma unroll
      for (int mi = 0; mi < 4; ++mi)
#pragma unroll
        for (int ni = 0; ni < 4; ++ni)
          acc[mi][ni] = __builtin_amdgcn_mfma_f32_16x16x32_bf16(
              af[mi][kk], bfr[ni][kk], acc[mi][ni], 0, 0, 0);
    asm volatile("s_barrier" ::: "memory");
  }
#pragma unroll
  for (int ni = 0; ni < 4; ++ni) {
    int gn = n0 + wc * 64 + ni * 16 + (lane & 15);
    float bv = bias[gn];
#pragma unroll
    for (int mi = 0; mi < 4; ++mi) {
      int gm0 = m0 + wr * 64 + mi * 16 + ((lane >> 4) << 2);
#pragma unroll
      for (int r = 0; r < 4; ++r)
        out[(size_t)(gm0 + r) * C_EMB + gn] = acc[mi][ni][r] + bv;
    }
  }
}

extern "C" void kernel_launch(void* const* d_in, const int* in_sizes, int n_in,
                              void* d_out, int out_size, void* d_ws, size_t ws_size,
                              hipStream_t stream) {
  const float* x = (const float*)d_in[0];
  const float* wk = (const float*)d_in[1];
  const float* wq = (const float*)d_in[2];
  const float* wv = (const float*)d_in[3];
  const float* wproj = (const float*)d_in[4];
  const float* bproj = (const float*)d_in[5];
  float* out = (float*)d_out;
  u16* ws = (u16*)d_ws;
  u16* kqv = ws;                               // 3 * BHTD bf16 (K,Q [bhtd]; V [bhdt])
  u16* attnb = ws + 3 * (size_t)BHTD;          // BHTD bf16 (attn out)
  u16* xb = attnb;                             // aliases attnb: xb dead before attn writes
  u16* wqkvt = attnb + (size_t)BHTD;           // 1152*384
  u16* wprojt = wqkvt + (size_t)N3 * C_EMB;    // 384*384
  prep_all<<<14592, 256, 0, stream>>>(x, wk, wq, wv, wproj, xb, wqkvt, wprojt);
  qkv_gemm<<<4608, 256, 0, stream>>>(xb, wqkvt, kqv);
  attn_kernel<<<1536, 512, 0, stream>>>(kqv, attnb);
  out_gemm<<<1536, 256, 0, stream>>>(attnb, wprojt, bproj, out);
}

// Round 17
// 174.671 us; speedup vs baseline: 1.2023x; 1.0855x over previous
//
#include <hip/hip_runtime.h>

typedef unsigned short u16;
typedef __bf16 bf16x8 __attribute__((ext_vector_type(8)));
typedef float f32x4 __attribute__((ext_vector_type(4)));

#define B_SZ 256
#define T_SZ 256
#define C_EMB 384
#define NHEAD 6
#define DHEAD 64
#define N3 1152
#define BHTD 25165824   // B*H*T*D elements per tensor
#define SCALE 0.05103103630798287f  // 384^-0.5
#define MASKV -3.0e4f   // causal-mask value: exp(MASKV) underflows to exact 0

// f32 -> bf16 RNE via compiler cast (single v_cvt instruction on gfx950)
__device__ __forceinline__ u16 f2bf(float f) {
  __bf16 b = (__bf16)f;
  return __builtin_bit_cast(u16, b);
}

__device__ __forceinline__ void gload_lds16(const void* g, void* l) {
  __builtin_amdgcn_global_load_lds((const __attribute__((address_space(1))) void*)g,
                                   (__attribute__((address_space(3))) void*)l, 16, 0, 0);
}

// ---------------- fused prep: x->bf16 AND weights->bf16 transposed ----------
__global__ __launch_bounds__(256) void prep_all(
    const float* __restrict__ x, const float* __restrict__ wk,
    const float* __restrict__ wq, const float* __restrict__ wv,
    const float* __restrict__ wproj,
    u16* __restrict__ xb, u16* __restrict__ wqkvt, u16* __restrict__ wprojt) {
  int bidx = blockIdx.x;
  if (bidx < 12288) {
    int i = bidx * 256 + threadIdx.x;   // unit of 8 floats
    float4 f0 = ((const float4*)x)[i * 2];
    float4 f1 = ((const float4*)x)[i * 2 + 1];
    uint4 p;
    p.x = (unsigned)f2bf(f0.x) | ((unsigned)f2bf(f0.y) << 16);
    p.y = (unsigned)f2bf(f0.z) | ((unsigned)f2bf(f0.w) << 16);
    p.z = (unsigned)f2bf(f1.x) | ((unsigned)f2bf(f1.y) << 16);
    p.w = (unsigned)f2bf(f1.z) | ((unsigned)f2bf(f1.w) << 16);
    ((uint4*)xb)[i] = p;
  } else {
    int i = (bidx - 12288) * 256 + threadIdx.x;
    if (i < N3 * C_EMB) {
      int n = i / C_EMB, c = i - n * C_EMB;
      int tensor = n >= 768 ? 2 : (n >= 384 ? 1 : 0);
      int r = n - tensor * 384;
      int h = r >> 6, d = r & 63;
      const float* w = tensor == 0 ? wk : (tensor == 1 ? wq : wv);
      float val = w[(h * C_EMB + c) * DHEAD + d];
      if (tensor == 0) val *= SCALE;   // fold 1/sqrt(C) into K
      wqkvt[i] = f2bf(val);
    } else {
      int ii = i - N3 * C_EMB;
      if (ii < C_EMB * C_EMB) {
        int n = ii / C_EMB, c = ii - n * C_EMB;
        wprojt[ii] = f2bf(wproj[c * C_EMB + n]);  // transpose
      }
    }
  }
}

// ---------------- QKV GEMM: 128x128 tile, BK=64, single-buffered (m97) ------
// FROZEN (round-9 verified; 822 TF = structure ceiling, retiles regress).
// K,Q stored [b][h][t][d]; V stored [b][h][d][t] (transposed).
__global__ __launch_bounds__(256, 4) void qkv_gemm(const u16* __restrict__ xb,
                                                   const u16* __restrict__ wt,
                                                   u16* __restrict__ kqv) {
  __shared__ __align__(16) u16 lA[128 * 64];
  __shared__ __align__(16) u16 lB[128 * 64];
  const int tid = threadIdx.x;
  const int lane = tid & 63, w = tid >> 6;
  int bid = blockIdx.x;
  int nb = (bid & 7) * 576 + (bid >> 3);
  int mt = nb / 9, nt = nb - mt * 9;
  const int n0 = nt * 128, m0 = mt * 128;
  const int wr = w >> 1, wc = w & 1;
  f32x4 acc[4][4] = {};
  for (int kt = 0; kt < 6; ++kt) {
    const int k0 = kt * 64;
#pragma unroll
    for (int it = 0; it < 4; ++it) {
      int ub = it * 256 + w * 64;
      int u = ub + lane;
      int row = u >> 3, cu = u & 7;
      int koff = k0 + ((cu ^ (row & 7)) << 3);
      gload_lds16(xb + (size_t)(m0 + row) * C_EMB + koff, lA + ub * 8);
      gload_lds16(wt + (size_t)(n0 + row) * C_EMB + koff, lB + ub * 8);
    }
    asm volatile("s_waitcnt vmcnt(0)" ::: "memory");
    asm volatile("s_barrier" ::: "memory");
    bf16x8 af[4][2], bfr[4][2];
#pragma unroll
    for (int mi = 0; mi < 4; ++mi) {
      int row = wr * 64 + mi * 16 + (lane & 15);
#pragma unroll
      for (int kk = 0; kk < 2; ++kk) {
        int cu = kk * 4 + (lane >> 4);
        af[mi][kk] = *(const bf16x8*)((const char*)lA + row * 128 + ((cu ^ (row & 7)) << 4));
      }
    }
#pragma unroll
    for (int ni = 0; ni < 4; ++ni) {
      int row = wc * 64 + ni * 16 + (lane & 15);
#pragma unroll
      for (int kk = 0; kk < 2; ++kk) {
        int cu = kk * 4 + (lane >> 4);
        bfr[ni][kk] = *(const bf16x8*)((const char*)lB + row * 128 + ((cu ^ (row & 7)) << 4));
      }
    }
#pragma unroll
    for (int kk = 0; kk < 2; ++kk)
#pragma unroll
      for (int mi = 0; mi < 4; ++mi)
#pragma unroll
        for (int ni = 0; ni < 4; ++ni)
          acc[mi][ni] = __builtin_amdgcn_mfma_f32_16x16x32_bf16(
              af[mi][kk], bfr[ni][kk], acc[mi][ni], 0, 0, 0);
    if (kt < 5)
      asm volatile("s_barrier" ::: "memory"); // LDS reuse fence (dead on last kt)
  }

  const int tensor = nt / 3;  // 128-tile lies in one tensor (384 = 3*128)
  if (tensor == 2) {
    // V^T store: vt[((b*6+h)*64 + d)*256 + t], 4 t-contiguous values packed
    u16* vt = kqv + 2 * (size_t)BHTD;
#pragma unroll
    for (int ni = 0; ni < 4; ++ni) {
      int r2 = n0 + wc * 64 + ni * 16 + (lane & 15) - 768;
      int h = r2 >> 6, d = r2 & 63;
#pragma unroll
      for (int mi = 0; mi < 4; ++mi) {
        int gm0 = m0 + wr * 64 + mi * 16 + ((lane >> 4) << 2);
        int b = gm0 >> 8, tt2 = gm0 & 255;
        ushort4 pk;
        pk.x = f2bf(acc[mi][ni][0]);
        pk.y = f2bf(acc[mi][ni][1]);
        pk.z = f2bf(acc[mi][ni][2]);
        pk.w = f2bf(acc[mi][ni][3]);
        *(ushort4*)(vt + ((size_t)(b * NHEAD + h) * 64 + d) * 256 + tt2) = pk;
      }
    }
  } else {
#pragma unroll
    for (int ni = 0; ni < 4; ++ni) {
      int gn = n0 + wc * 64 + ni * 16 + (lane & 15);
      int r2 = gn - tensor * 384;
      int h = r2 >> 6, d = r2 & 63;
#pragma unroll
      for (int mi = 0; mi < 4; ++mi) {
        int gm0 = m0 + wr * 64 + mi * 16 + ((lane >> 4) << 2);
#pragma unroll
        for (int r = 0; r < 4; ++r) {
          int m = gm0 + r;
          int b = m >> 8, t = m & 255;
          kqv[(size_t)tensor * BHTD + ((((b * NHEAD + h) << 8) + t) << 6) + d] =
              f2bf(acc[mi][ni][r]);
        }
      }
    }
  }
}

// ---------------- causal flash attention, S[t,s] = Ksc[t]·Q[s] ----
// ROUND-14 VERIFIED STRUCTURE (best: 176.1us total). ONE block per (b,h).
// Prologue overlap: issue K, Q-rows-0-63, Q-rest, V; wait vmcnt(7) (K+Q0)
// -> QK(0)+softmax overlaps remaining Q + all V. Complementary row-groups
// t=w*16 / 240-w*16: exactly 5 causal tiles per wave. Barrier-free s-loop.
__global__ __launch_bounds__(512, 2) void attn_kernel(const u16* __restrict__ kqv,
                                                      u16* __restrict__ attnb) {
  __shared__ __align__(16) u16 lQ[256 * 64];    // 32KB, [s][d] swz
  __shared__ __align__(16) u16 lVt[64 * 256];   // 32KB, [d][s] stride 512B swz
  __shared__ __align__(16) char lP[8 * 16 * 128]; // 16KB, per-wave XOR-swz
  const int tid = threadIdx.x;
  const int lane = tid & 63, w = tid >> 6;
  int bid = blockIdx.x;                       // 1536 = 8 * 192
  const int bh = (bid & 7) * 192 + (bid >> 3);
  const u16* Kb = kqv + (size_t)bh * (T_SZ * DHEAD);
  const u16* Qb = kqv + (size_t)BHTD + (size_t)bh * (T_SZ * DHEAD);
  const u16* Vb = kqv + 2 * (size_t)BHTD + (size_t)bh * (DHEAD * T_SZ);  // [d][t]

  const int t0w0 = w * 16;                    // row-group 0 (early rows)
  const int t0w1 = 240 - w * 16;              // row-group 1 (complement: balance)
  const int tg00 = t0w0 + ((lane >> 4) << 2);
  const int tg01 = t0w1 + ((lane >> 4) << 2);

  // --- issue order (fenced): K->regs (oldest), Q rows 0-63, Q rest, V ---
  bf16x8 af0[2], af1[2];
  {
    const u16* kr0 = Kb + (size_t)(t0w0 + (lane & 15)) * DHEAD;
    const u16* kr1 = Kb + (size_t)(t0w1 + (lane & 15)) * DHEAD;
    af0[0] = *(const bf16x8*)(kr0 + ((lane >> 4) << 3));
    af0[1] = *(const bf16x8*)(kr0 + 32 + ((lane >> 4) << 3));
    af1[0] = *(const bf16x8*)(kr1 + ((lane >> 4) << 3));
    af1[1] = *(const bf16x8*)(kr1 + 32 + ((lane >> 4) << 3));
  }
  asm volatile("" ::: "memory");
  {                                           // Q tile 0: rows 0-63 (1 load)
    int u = tid;
    int row = u >> 3, cu = u & 7;
    gload_lds16(Qb + (size_t)row * DHEAD + ((cu ^ (row & 7)) << 3), lQ + u * 8);
  }
  asm volatile("" ::: "memory");
#pragma unroll
  for (int it = 1; it < 4; ++it) {            // Q rows 64-255 (3 loads)
    int u = it * 512 + tid;
    int row = u >> 3, cu = u & 7;
    gload_lds16(Qb + (size_t)row * DHEAD + ((cu ^ (row & 7)) << 3), lQ + u * 8);
  }
  asm volatile("" ::: "memory");
#pragma unroll
  for (int it = 0; it < 4; ++it) {            // V^T: 64 rows x 256s, swz/128B win
    int u = it * 512 + tid;
    int row = u >> 5, cu = u & 31;
    gload_lds16(Vb + (size_t)row * T_SZ + ((cu >> 3) << 6) + (((cu & 7) ^ (row & 7)) << 3),
                lVt + u * 8);
  }
  // K(4)+Q0(1) retired; Q-rest(3)+V(4)=7 still in flight
  asm volatile("s_waitcnt vmcnt(7)" ::: "memory");
  asm volatile("s_barrier" ::: "memory");            // lQ rows 0-63 ready

  char* lPw = lP + w * (16 * 128);
  f32x4 oacc0[4] = {}, oacc1[4] = {};
  float lrowp0[4] = {0.f, 0.f, 0.f, 0.f};
  float lrowp1[4] = {0.f, 0.f, 0.f, 0.f};
  const int last0 = t0w0 >> 6;                // 0..1
  const int last1 = t0w1 >> 6;                // 3..2  (complement)

#define QK_TILE(s0_, af_, t0w_, tg0_, lrp_) { \
    f32x4 sacc[4] = {}; \
    __builtin_amdgcn_s_setprio(1); \
    _Pragma("unroll") for (int ni = 0; ni < 4; ++ni) { \
      int row = (s0_) + ni * 16 + (lane & 15); \
      _Pragma("unroll") for (int kk = 0; kk < 2; ++kk) { \
        int cu = kk * 4 + (lane >> 4); \
        bf16x8 bq = *(const bf16x8*)((const char*)lQ + row * 128 + ((cu ^ (row & 7)) << 4)); \
        sacc[ni] = __builtin_amdgcn_mfma_f32_16x16x32_bf16(af_[kk], bq, sacc[ni], 0, 0, 0); \
      } \
    } \
    __builtin_amdgcn_s_setprio(0); \
    if ((s0_) + 63 > (t0w_)) { \
      _Pragma("unroll") for (int ni = 0; ni < 4; ++ni) { \
        int sg = (s0_) + ni * 16 + (lane & 15); \
        _Pragma("unroll") for (int r = 0; r < 4; ++r) \
          if (sg > (tg0_) + r) sacc[ni][r] = MASKV; \
      } \
    } \
    _Pragma("unroll") for (int ni = 0; ni < 4; ++ni) { \
      int scol = ni * 16 + (lane & 15); \
      _Pragma("unroll") for (int r = 0; r < 4; ++r) { \
        float p = __expf(sacc[ni][r]); \
        lrp_[r] += p; \
        int trow = ((lane >> 4) << 2) + r; \
        *(u16*)(lPw + trow * 128 + ((scol * 2) ^ ((trow & 7) << 4))) = f2bf(p); \
      } \
    } }

#define PV_TILE(s0_, oacc_) { \
    bf16x8 pa[2]; \
    int trow = lane & 15; \
    _Pragma("unroll") for (int kk = 0; kk < 2; ++kk) { \
      int cu = kk * 4 + (lane >> 4); \
      pa[kk] = *(const bf16x8*)(lPw + trow * 128 + (((cu) << 4) ^ ((trow & 7) << 4))); \
    } \
    __builtin_amdgcn_s_setprio(1); \
    _Pragma("unroll") for (int nd = 0; nd < 4; ++nd) { \
      int drow = nd * 16 + (lane & 15); \
      _Pragma("unroll") for (int kk = 0; kk < 2; ++kk) { \
        int cu = kk * 4 + (lane >> 4); \
        bf16x8 vb = *(const bf16x8*)((const char*)lVt + drow * 512 + (s0_) * 2 + \
                                     (((cu) ^ (drow & 7)) << 4)); \
        oacc_[nd] = __builtin_amdgcn_mfma_f32_16x16x32_bf16(pa[kk], vb, oacc_[nd], 0, 0, 0); \
      } \
    } \
    __builtin_amdgcn_s_setprio(0); }

  // row-group 0, tile 0: QK+softmax overlaps Q-rest + V in-flight loads
  QK_TILE(0, af0, t0w0, tg00, lrowp0)
  asm volatile("s_waitcnt vmcnt(0)" ::: "memory");   // Q-rest + V landed
  asm volatile("s_barrier" ::: "memory");            // lQ + lVt fully ready
  PV_TILE(0, oacc0)
  for (int si = 1; si <= last0; ++si) {
    const int s0 = si << 6;
    QK_TILE(s0, af0, t0w0, tg00, lrowp0)
    PV_TILE(s0, oacc0)
  }
  // row-group 1: barrier-free
  for (int si = 0; si <= last1; ++si) {
    const int s0 = si << 6;
    QK_TILE(s0, af1, t0w1, tg01, lrowp1)
    PV_TILE(s0, oacc1)
  }
#undef QK_TILE
#undef PV_TILE

  // final cross-lane row-sum reduce (once per group)
#pragma unroll
  for (int r = 0; r < 4; ++r) {
#pragma unroll
    for (int off = 1; off < 16; off <<= 1) {
      lrowp0[r] += __shfl_xor(lrowp0[r], off);
      lrowp1[r] += __shfl_xor(lrowp1[r], off);
    }
  }
  const int b = bh / NHEAD, h = bh - (bh / NHEAD) * NHEAD;
#pragma unroll
  for (int r = 0; r < 4; ++r) {
    int t0_ = tg00 + r, t1_ = tg01 + r;
    float inv0 = 1.0f / lrowp0[r];
    float inv1 = 1.0f / lrowp1[r];
#pragma unroll
    for (int nd = 0; nd < 4; ++nd) {
      int col = h * 64 + nd * 16 + (lane & 15);
      attnb[((size_t)(b * T_SZ + t0_)) * C_EMB + col] = f2bf(oacc0[nd][r] * inv0);
      attnb[((size_t)(b * T_SZ + t1_)) * C_EMB + col] = f2bf(oacc1[nd][r] * inv1);
    }
  }
}

// ---------------- out projection: 128x128 tile, single-buffered -------------
__global__ __launch_bounds__(256, 4) void out_gemm(const u16* __restrict__ a,
                                                   const u16* __restrict__ wt,
                                                   const float* __restrict__ bias,
                                                   float* __restrict__ out) {
  __shared__ __align__(16) u16 lA[128 * 64];
  __shared__ __align__(16) u16 lB[128 * 64];
  const int tid = threadIdx.x;
  const int lane = tid & 63, w = tid >> 6;
  int bid = blockIdx.x;
  int nb = (bid & 7) * 192 + (bid >> 3);
  int mt = nb / 3, nt = nb - mt * 3;
  const int n0 = nt * 128, m0 = mt * 128;
  const int wr = w >> 1, wc = w & 1;
  f32x4 acc[4][4] = {};
  for (int kt = 0; kt < 6; ++kt) {
    const int k0 = kt * 64;
#pragma unroll
    for (int it = 0; it < 4; ++it) {
      int ub = it * 256 + w * 64;
      int u = ub + lane;
      int row = u >> 3, cu = u & 7;
      int koff = k0 + ((cu ^ (row & 7)) << 3);
      gload_lds16(a + (size_t)(m0 + row) * C_EMB + koff, lA + ub * 8);
      gload_lds16(wt + (size_t)(n0 + row) * C_EMB + koff, lB + ub * 8);
    }
    asm volatile("s_waitcnt vmcnt(0)" ::: "memory");
    asm volatile("s_barrier" ::: "memory");
    bf16x8 af[4][2], bfr[4][2];
#pragma unroll
    for (int mi = 0; mi < 4; ++mi) {
      int row = wr * 64 + mi * 16 + (lane & 15);
#pragma unroll
      for (int kk = 0; kk < 2; ++kk) {
        int cu = kk * 4 + (lane >> 4);
        af[mi][kk] = *(const bf16x8*)((const char*)lA + row * 128 + ((cu ^ (row & 7)) << 4));
      }
    }
#pragma unroll
    for (int ni = 0; ni < 4; ++ni) {
      int row = wc * 64 + ni * 16 + (lane & 15);
#pragma unroll
      for (int kk = 0; kk < 2; ++kk) {
        int cu = kk * 4 + (lane >> 4);
        bfr[ni][kk] = *(const bf16x8*)((const char*)lB + row * 128 + ((cu ^ (row & 7)) << 4));
      }
    }
#pragma unroll
    for (int kk = 0; kk < 2; ++kk)
#pragma unroll
      for (int mi = 0; mi < 4; ++mi)
#pragma unroll
        for (int ni = 0; ni < 4; ++ni)
          acc[mi][ni] = __builtin_amdgcn_mfma_f32_16x16x32_bf16(
              af[mi][kk], bfr[ni][kk], acc[mi][ni], 0, 0, 0);
    if (kt < 5)
      asm volatile("s_barrier" ::: "memory");
  }
#pragma unroll
  for (int ni = 0; ni < 4; ++ni) {
    int gn = n0 + wc * 64 + ni * 16 + (lane & 15);
    float bv = bias[gn];
#pragma unroll
    for (int mi = 0; mi < 4; ++mi) {
      int gm0 = m0 + wr * 64 + mi * 16 + ((lane >> 4) << 2);
#pragma unroll
      for (int r = 0; r < 4; ++r)
        out[(size_t)(gm0 + r) * C_EMB + gn] = acc[mi][ni][r] + bv;
    }
  }
}

extern "C" void kernel_launch(void* const* d_in, const int* in_sizes, int n_in,
                              void* d_out, int out_size, void* d_ws, size_t ws_size,
                              hipStream_t stream) {
  const float* x = (const float*)d_in[0];
  const float* wk = (const float*)d_in[1];
  const float* wq = (const float*)d_in[2];
  const float* wv = (const float*)d_in[3];
  const float* wproj = (const float*)d_in[4];
  const float* bproj = (const float*)d_in[5];
  float* out = (float*)d_out;
  u16* ws = (u16*)d_ws;
  u16* kqv = ws;                               // 3 * BHTD bf16 (K,Q [bhtd]; V [bhdt])
  u16* attnb = ws + 3 * (size_t)BHTD;          // BHTD bf16 (attn out)
  u16* xb = attnb;                             // aliases attnb: xb dead before attn writes
  u16* wqkvt = attnb + (size_t)BHTD;           // 1152*384
  u16* wprojt = wqkvt + (size_t)N3 * C_EMB;    // 384*384
  prep_all<<<14592, 256, 0, stream>>>(x, wk, wq, wv, wproj, xb, wqkvt, wprojt);
  qkv_gemm<<<4608, 256, 0, stream>>>(xb, wqkvt, kqv);
  attn_kernel<<<1536, 512, 0, stream>>>(kqv, attnb);
  out_gemm<<<1536, 256, 0, stream>>>(attnb, wprojt, bproj, out);
}